// Round 7
// baseline (154.131 us; speedup 1.0000x reference)
//
#include <hip/hip_runtime.h>
#include <stdint.h>

#define T_STEPS 100
#define BB 4
#define NN 512
#define KK 10
#define TBTOT (T_STEPS * BB)        // 400
#define LLT_ELT ((size_t)TBTOT * NN) // 204800 doubles

// ---------------- threefry2x32 (JAX-compatible, 20 rounds) ----------------
__device__ __forceinline__ uint32_t rotl32(uint32_t v, int d) {
  return (v << d) | (v >> (32 - d));
}

__device__ __forceinline__ void tf2x32(uint32_t k0, uint32_t k1,
                                       uint32_t& x0, uint32_t& x1) {
  uint32_t k2 = k0 ^ k1 ^ 0x1BD11BDAu;
  x0 += k0; x1 += k1;
#define TFR(r) { x0 += x1; x1 = rotl32(x1, r); x1 ^= x0; }
  TFR(13) TFR(15) TFR(26) TFR(6)   x0 += k1; x1 += k2 + 1u;
  TFR(17) TFR(29) TFR(16) TFR(24)  x0 += k2; x1 += k0 + 2u;
  TFR(13) TFR(15) TFR(26) TFR(6)   x0 += k0; x1 += k1 + 3u;
  TFR(17) TFR(29) TFR(16) TFR(24)  x0 += k1; x1 += k2 + 4u;
  TFR(13) TFR(15) TFR(26) TFR(6)   x0 += k2; x1 += k0 + 5u;
#undef TFR
}

__device__ __forceinline__ float bits_to_u01(uint32_t bits) {
  return __fsub_rn(__uint_as_float((bits >> 9) | 0x3f800000u), 1.0f);
}

// XLA ErfInv32 (Giles), w = -log((1-x)(1+x)) exactly as ElementalIrEmitter
__device__ __forceinline__ float erfinv_f32(float x) {
  float w = -logf(__fmul_rn(__fsub_rn(1.0f, x), __fadd_rn(1.0f, x)));
  float p;
  if (w < 5.0f) {
    w = __fsub_rn(w, 2.5f);
    p = 2.81022636e-08f;
    p = __fadd_rn(__fmul_rn(p, w), 3.43273939e-07f);
    p = __fadd_rn(__fmul_rn(p, w), -3.5233877e-06f);
    p = __fadd_rn(__fmul_rn(p, w), -4.39150654e-06f);
    p = __fadd_rn(__fmul_rn(p, w), 0.00021858087f);
    p = __fadd_rn(__fmul_rn(p, w), -0.00125372503f);
    p = __fadd_rn(__fmul_rn(p, w), -0.00417768164f);
    p = __fadd_rn(__fmul_rn(p, w), 0.246640727f);
    p = __fadd_rn(__fmul_rn(p, w), 1.50140941f);
  } else {
    w = __fsub_rn(sqrtf(w), 3.0f);
    p = -0.000200214257f;
    p = __fadd_rn(__fmul_rn(p, w), 0.000100950558f);
    p = __fadd_rn(__fmul_rn(p, w), 0.00134934322f);
    p = __fadd_rn(__fmul_rn(p, w), -0.00367342844f);
    p = __fadd_rn(__fmul_rn(p, w), 0.00573950773f);
    p = __fadd_rn(__fmul_rn(p, w), -0.0076224613f);
    p = __fadd_rn(__fmul_rn(p, w), 0.00943887047f);
    p = __fadd_rn(__fmul_rn(p, w), 1.00167406f);
    p = __fadd_rn(__fmul_rn(p, w), 2.83297682f);
  }
  return __fmul_rn(p, x);
}

// fast sigmoid: 1/(1+exp(-x)) via native exp + native rcp (~1-2 ulp)
__device__ __forceinline__ float fast_sigmoid(float x) {
  float e = __expf(-x);
  return __builtin_amdgcn_rcpf(__fadd_rn(1.0f, e));
}

// DPP-based partial butterfly stage: x += dpp(x)
template <int CTRL>
__device__ __forceinline__ float dpp_add(float x) {
  int v = __builtin_amdgcn_update_dpp(0, __float_as_int(x), CTRL, 0xF, 0xF, true);
  return __fadd_rn(x, __int_as_float(v));
}
__device__ __forceinline__ float readlane_f(float x, int lane) {
  return __int_as_float(__builtin_amdgcn_readlane(__float_as_int(x), lane));
}

// ---------------- Kernel A: softmax-mixture mean/std + L(f32) ---------------
__global__ void prep_kernel(const float* __restrict__ mu,
                            const float* __restrict__ sig,
                            const float* __restrict__ pi,
                            float* __restrict__ sm, float* __restrict__ ss,
                            float* __restrict__ Lf) {
  int m = blockIdx.x * blockDim.x + threadIdx.x;
  if (m >= BB * NN) return;
  const float* pp = pi + m * KK;
  float mx = pp[0];
  for (int k = 1; k < KK; k++) mx = fmaxf(mx, pp[k]);
  float e[KK]; float s = 0.0f;
  for (int k = 0; k < KK; k++) { e[k] = expf(__fsub_rn(pp[k], mx)); s = __fadd_rn(s, e[k]); }
  float smv = 0.0f, ssv = 0.0f, eps = 0.0f;
  for (int k = 0; k < KK; k++) {
    float p = e[k] / s;
    smv = __fadd_rn(smv, __fmul_rn(p, mu[m * KK + k]));
    ssv = __fadd_rn(ssv, __fmul_rn(p, sig[m * KK + k]));
    eps = __fadd_rn(eps, pp[k]);
  }
  sm[m] = smv; ss[m] = ssv;
  float ep = fminf(fmaxf(eps, 1e-8f), 1.0f);
  float lep = logf(ep);
  float l1 = logf(__fsub_rn(1.0f, ep));
  Lf[m] = (float)((double)lep - (double)l1);
}

// -------- Kernel B: JAX partitionable-threefry RNG -> pm table + uniforms ----
__global__ void rng_kernel(const float* __restrict__ sm,
                           const float* __restrict__ ss,
                           float* __restrict__ pm, float* __restrict__ uacc) {
  int id = blockIdx.x * blockDim.x + threadIdx.x;
  if (id >= T_STEPS * BB * NN) return;
  int t = id >> 11;        // /2048
  int m = id & 2047;       // b*512+n

  uint32_t kk0 = 0u, kk1 = (uint32_t)t;
  tf2x32(0u, 42u, kk0, kk1);
  uint32_t n0 = 0u, n1 = 0u; tf2x32(kk0, kk1, n0, n1);   // k_noise
  uint32_t y0 = 0u, y1 = (uint32_t)m;
  tf2x32(n0, n1, y0, y1);
  uint32_t bits = y0 ^ y1;

  float u01 = bits_to_u01(bits);
  const float lo = -0.99999994f;  // nextafter(-1,0) f32; span rounds to 2.0f
  float u = fmaxf(lo, __fadd_rn(__fmul_rn(u01, 2.0f), lo));
  float z = __fmul_rn(1.41421356237309515f, erfinv_f32(u));
  pm[id] = __fadd_rn(sm[m], __fmul_rn(z, ss[m]));

  if (m < 4) {
    uint32_t u0 = 0u, u1 = 1u; tf2x32(kk0, kk1, u0, u1); // k_unif
    uint32_t c0 = 0u, c1 = (uint32_t)m;
    tf2x32(u0, u1, c0, c1);
    uacc[t * 4 + m] = bits_to_u01(c0 ^ c1);
  }
}

// ------- Kernel C: partial llt[t][b][j] = sum_{i in chunk} sgm(pm_i pm_j)*L[b,i]
template <int SPLIT>
__global__ __launch_bounds__(512) void ll_kernel(const float* __restrict__ pm,
                                                 const float* __restrict__ Lf,
                                                 const float* __restrict__ A0,
                                                 double* __restrict__ llt_p,
                                                 double* __restrict__ ll0_p) {
  constexpr int CH = NN / SPLIT;
  __shared__ float spm[CH];
  __shared__ float sLc[CH];
  int j = threadIdx.x;
  int bi = blockIdx.x;
  if (bi < TBTOT * SPLIT) {
    int tb = bi / SPLIT;
    int s = bi - tb * SPLIT;
    int b = tb & 3;
    int i0 = s * CH;
    if (j < CH) {
      spm[j] = pm[tb * NN + i0 + j];
      sLc[j] = Lf[b * NN + i0 + j];
    }
    float pmj = pm[tb * NN + j];
    __syncthreads();
    double acc = 0.0;
    #pragma unroll 8
    for (int i = 0; i < CH; i += 2) {
      float x0 = __fmul_rn(spm[i], pmj);
      float x1 = __fmul_rn(spm[i + 1], pmj);
      float t0 = __fmul_rn(fast_sigmoid(x0), sLc[i]);
      float t1 = __fmul_rn(fast_sigmoid(x1), sLc[i + 1]);
      acc += (double)__fadd_rn(t0, t1);
    }
    llt_p[(size_t)s * LLT_ELT + (size_t)tb * NN + j] = acc;
  } else {
    int bi2 = bi - TBTOT * SPLIT;
    int b = bi2 / SPLIT;
    int s = bi2 - b * SPLIT;
    int i0 = s * CH;
    if (j < CH) sLc[j] = Lf[b * NN + i0 + j];
    __syncthreads();
    double acc = 0.0;
    #pragma unroll 4
    for (int i = 0; i < CH; i++) {
      acc += (double)A0[(size_t)(i0 + i) * NN + j] * (double)sLc[i];
    }
    ll0_p[s * (BB * NN) + b * NN + j] = acc;
  }
}

// ------- Kernel C2: combine partials; also emit Tsum[t][j] = sum_b llt ------
template <int SPLIT>
__global__ __launch_bounds__(512) void combine_kernel(const double* __restrict__ llt_p,
                                                      const double* __restrict__ ll0_p,
                                                      double* __restrict__ llt,
                                                      double* __restrict__ ll0,
                                                      double* __restrict__ tsum) {
  int bi = blockIdx.x;
  int j = threadIdx.x;
  if (bi < T_STEPS) {
    double tj = 0.0;
    #pragma unroll
    for (int b = 0; b < BB; b++) {
      size_t idx = ((size_t)bi * BB + b) * NN + j;
      double a = llt_p[idx];
      #pragma unroll
      for (int s = 1; s < SPLIT; s++) a += llt_p[(size_t)s * LLT_ELT + idx];
      llt[idx] = a;
      tj += a;
    }
    tsum[(size_t)bi * NN + j] = tj;
  } else {
    #pragma unroll
    for (int b = 0; b < BB; b++) {
      int idx = b * NN + j;
      double a = ll0_p[idx];
      #pragma unroll
      for (int s = 1; s < SPLIT; s++) a += ll0_p[s * (BB * NN) + idx];
      ll0[idx] = a;
    }
  }
}

// ------- Kernel D: sequential MCMC chain, SINGLE WAVE, depth-3 prefetch -----
// lane g owns j = 128k + 2g + h  (k=0..3, h=0..1).  No barriers, no LDS
// reduction: butterfly = 4 DPP stages (VALU) + readlane{0,16,32,48} + 3 adds.
// diff uses precomputed Tsum and incrementally-maintained C[j] = sum_b llcur.
struct ChainBuf {
  double2 ll[4][4];   // [batch][k]
  double2 ts[4];      // Tsum [k]
};

#define CH_LOAD(BUF, T)                                                      \
  {                                                                          \
    _Pragma("unroll")                                                        \
    for (int b = 0; b < 4; b++) {                                            \
      _Pragma("unroll")                                                      \
      for (int k = 0; k < 4; k++)                                            \
        BUF.ll[b][k] = llt2[((size_t)(T) * 4 + b) * 256 + k * 64 + g];       \
    }                                                                        \
    _Pragma("unroll")                                                        \
    for (int k = 0; k < 4; k++)                                              \
      BUF.ts[k] = tsum2[(size_t)(T) * 256 + k * 64 + g];                     \
  }

#define CH_ACC(BUF, B)                                                       \
  {                                                                          \
    _Pragma("unroll")                                                        \
    for (int k = 0; k < 4; k++) {                                            \
      C[k].x += BUF.ll[B][k].x - cur[B][k].x;                                \
      C[k].y += BUF.ll[B][k].y - cur[B][k].y;                                \
      cur[B][k] = BUF.ll[B][k];                                              \
    }                                                                        \
  }

#define CH_STEP(BUF, T)                                                      \
  {                                                                          \
    float4 ua = sua[T];                                                      \
    float e0x = fminf(__expf((float)(BUF.ts[0].x - C[0].x)), 1.0f);          \
    float e0y = fminf(__expf((float)(BUF.ts[0].y - C[0].y)), 1.0f);          \
    float e1x = fminf(__expf((float)(BUF.ts[1].x - C[1].x)), 1.0f);          \
    float e1y = fminf(__expf((float)(BUF.ts[1].y - C[1].y)), 1.0f);          \
    float e2x = fminf(__expf((float)(BUF.ts[2].x - C[2].x)), 1.0f);          \
    float e2y = fminf(__expf((float)(BUF.ts[2].y - C[2].y)), 1.0f);          \
    float e3x = fminf(__expf((float)(BUF.ts[3].x - C[3].x)), 1.0f);          \
    float e3y = fminf(__expf((float)(BUF.ts[3].y - C[3].y)), 1.0f);          \
    float ps = __fadd_rn(__fadd_rn(__fadd_rn(e0x, e0y), __fadd_rn(e1x, e1y)),\
                         __fadd_rn(__fadd_rn(e2x, e2y), __fadd_rn(e3x, e3y)));\
    ps = dpp_add<0xB1>(ps);   /* quad_perm [1,0,3,2]  : xor1 */              \
    ps = dpp_add<0x4E>(ps);   /* quad_perm [2,3,0,1]  : xor2 */              \
    ps = dpp_add<0x141>(ps);  /* ROW_HALF_MIRROR      : pairs across 4s */   \
    ps = dpp_add<0x140>(ps);  /* ROW_MIRROR           : pairs across 8s */   \
    float s0 = readlane_f(ps, 0), s1 = readlane_f(ps, 16);                   \
    float s2 = readlane_f(ps, 32), s3 = readlane_f(ps, 48);                  \
    float tot = __fadd_rn(__fadd_rn(s0, s1), __fadd_rn(s2, s3));             \
    float ratio = __fmul_rn(tot, 1.0f / 512.0f);                             \
    if (ua.x < ratio) { st.x = (T); CH_ACC(BUF, 0) }                         \
    if (ua.y < ratio) { st.y = (T); CH_ACC(BUF, 1) }                         \
    if (ua.z < ratio) { st.z = (T); CH_ACC(BUF, 2) }                         \
    if (ua.w < ratio) { st.w = (T); CH_ACC(BUF, 3) }                         \
    if (g == 0) sst[T] = st;                                                 \
  }

__global__ __launch_bounds__(64) void chain_kernel(const double* __restrict__ llt,
                                                   const double* __restrict__ tsum,
                                                   const double* __restrict__ ll0,
                                                   const float* __restrict__ uacc,
                                                   int* __restrict__ counts) {
  __shared__ float4 sua[T_STEPS];
  __shared__ int4 sst[T_STEPS];
  __shared__ int scnt[BB * (T_STEPS + 1)];
  int g = threadIdx.x;

  const float4* uacc4 = (const float4*)uacc;
  for (int t = g; t < T_STEPS; t += 64) sua[t] = uacc4[t];

  const double2* llt2  = (const double2*)llt;
  const double2* tsum2 = (const double2*)tsum;
  const double2* ll02  = (const double2*)ll0;

  double2 cur[4][4];
  #pragma unroll
  for (int b = 0; b < 4; b++)
    #pragma unroll
    for (int k = 0; k < 4; k++) cur[b][k] = ll02[b * 256 + k * 64 + g];
  double2 C[4];
  #pragma unroll
  for (int k = 0; k < 4; k++) {
    C[k].x = (cur[0][k].x + cur[1][k].x) + (cur[2][k].x + cur[3][k].x);
    C[k].y = (cur[0][k].y + cur[1][k].y) + (cur[2][k].y + cur[3][k].y);
  }
  int4 st = make_int4(-1, -1, -1, -1);

  ChainBuf R0, R1, R2;
  CH_LOAD(R0, 0)
  CH_LOAD(R1, 1)
  CH_LOAD(R2, 2)
  __syncthreads();  // single wave; orders sua writes (cheap)

  for (int t = 0; t < 99; t += 3) {
    CH_STEP(R0, t)
    CH_LOAD(R0, t + 3)                        // t+3 <= 99 always
    CH_STEP(R1, t + 1)
    if (t + 4 < T_STEPS) CH_LOAD(R1, t + 4)
    CH_STEP(R2, t + 2)
    if (t + 5 < T_STEPS) CH_LOAD(R2, t + 5)
  }
  CH_STEP(R0, 99)

  __syncthreads();
  for (int s = g; s < BB * (T_STEPS + 1); s += 64) scnt[s] = 0;
  __syncthreads();
  for (int t = g; t < T_STEPS; t += 64) {
    int4 s4 = sst[t];
    atomicAdd(&scnt[0 * (T_STEPS + 1) + s4.x + 1], 1);
    atomicAdd(&scnt[1 * (T_STEPS + 1) + s4.y + 1], 1);
    atomicAdd(&scnt[2 * (T_STEPS + 1) + s4.z + 1], 1);
    atomicAdd(&scnt[3 * (T_STEPS + 1) + s4.w + 1], 1);
  }
  __syncthreads();
  for (int s = g; s < BB * (T_STEPS + 1); s += 64) counts[s] = scnt[s];
}

// ---------------- Kernel E: acc = sum_states count * A_state / num_samples --
__global__ __launch_bounds__(512) void out_kernel(const float* __restrict__ pm,
                                                  const float* __restrict__ A0,
                                                  const int* __restrict__ counts,
                                                  float* __restrict__ out) {
  __shared__ int scnt[T_STEPS + 1];
  int b = blockIdx.x >> 9;
  int i = blockIdx.x & 511;
  int j = threadIdx.x;
  if (j < T_STEPS + 1) scnt[j] = counts[b * (T_STEPS + 1) + j];
  __syncthreads();
  float r = (float)scnt[0] * A0[(size_t)i * NN + j];
  #pragma unroll 4
  for (int t = 0; t < T_STEPS; t++) {
    int c = scnt[t + 1];
    if (c) {
      float x = __fmul_rn(pm[(size_t)(t * BB + b) * NN + i],
                          pm[(size_t)(t * BB + b) * NN + j]);
      r += (float)c * fast_sigmoid(x);
    }
  }
  out[((size_t)b * NN + i) * NN + j] = r * 0.01f;
}

extern "C" void kernel_launch(void* const* d_in, const int* in_sizes, int n_in,
                              void* d_out, int out_size, void* d_ws, size_t ws_size,
                              hipStream_t stream) {
  const float* mu  = (const float*)d_in[0];
  const float* sig = (const float*)d_in[1];
  const float* pi  = (const float*)d_in[2];
  const float* A0  = (const float*)d_in[3];

  char* ws = (char*)d_ws;
  size_t off = 0;
  auto alloc = [&](size_t bytes) -> char* {
    char* p = ws + off;
    off += (bytes + 255) & ~(size_t)255;
    return p;
  };
  double* llt  = (double*)alloc(LLT_ELT * 8);             // 1,638,400
  double* ll0  = (double*)alloc(BB * NN * 8);             // 16,384
  double* tsum = (double*)alloc((size_t)T_STEPS * NN * 8);// 409,600
  float*  pm   = (float*)alloc(LLT_ELT * 4);              // 819,200
  float*  Lf   = (float*)alloc(BB * NN * 4);
  float*  sm   = (float*)alloc(BB * NN * 4);
  float*  ssv  = (float*)alloc(BB * NN * 4);
  float*  uacc = (float*)alloc(T_STEPS * 4 * 4);
  int*    cnts = (int*)alloc(BB * (T_STEPS + 1) * 4);
  size_t fixed_end = off;
  float*  outp = (float*)d_out;

  // choose SPLIT by available scratch for partial buffers
  size_t part4 = 4 * LLT_ELT * 8 + 4 * BB * NN * 8 + 1024;
  size_t part2 = 2 * LLT_ELT * 8 + 2 * BB * NN * 8 + 1024;
  int split = (ws_size >= fixed_end + part4) ? 4
            : (ws_size >= fixed_end + part2) ? 2 : 1;

  double* llt_p;
  double* ll0_p;
  if (split > 1) {
    llt_p = (double*)alloc((size_t)split * LLT_ELT * 8);
    ll0_p = (double*)alloc((size_t)split * BB * NN * 8);
  } else {
    llt_p = llt;  // write directly; combine still builds tsum
    ll0_p = ll0;
  }

  prep_kernel<<<8, 256, 0, stream>>>(mu, sig, pi, sm, ssv, Lf);
  rng_kernel<<<(T_STEPS * BB * NN + 255) / 256, 256, 0, stream>>>(sm, ssv, pm, uacc);
  if (split == 4) {
    ll_kernel<4><<<(TBTOT + BB) * 4, 512, 0, stream>>>(pm, Lf, A0, llt_p, ll0_p);
    combine_kernel<4><<<T_STEPS + 1, 512, 0, stream>>>(llt_p, ll0_p, llt, ll0, tsum);
  } else if (split == 2) {
    ll_kernel<2><<<(TBTOT + BB) * 2, 512, 0, stream>>>(pm, Lf, A0, llt_p, ll0_p);
    combine_kernel<2><<<T_STEPS + 1, 512, 0, stream>>>(llt_p, ll0_p, llt, ll0, tsum);
  } else {
    ll_kernel<1><<<TBTOT + BB, 512, 0, stream>>>(pm, Lf, A0, llt_p, ll0_p);
    combine_kernel<1><<<T_STEPS + 1, 512, 0, stream>>>(llt_p, ll0_p, llt, ll0, tsum);
  }
  chain_kernel<<<1, 64, 0, stream>>>(llt, tsum, ll0, uacc, cnts);
  out_kernel<<<BB * NN, 512, 0, stream>>>(pm, A0, cnts, outp);
}

// Round 8
// 147.814 us; speedup vs baseline: 1.0427x; 1.0427x over previous
//
#include <hip/hip_runtime.h>
#include <stdint.h>

#define T_STEPS 100
#define BB 4
#define NN 512
#define KK 10
#define TBTOT (T_STEPS * BB)        // 400
#define LLT_ELT ((size_t)TBTOT * NN) // 204800 elements

typedef float f4 __attribute__((ext_vector_type(4)));

// ---------------- threefry2x32 (JAX-compatible, 20 rounds) ----------------
__device__ __forceinline__ uint32_t rotl32(uint32_t v, int d) {
  return (v << d) | (v >> (32 - d));
}

__device__ __forceinline__ void tf2x32(uint32_t k0, uint32_t k1,
                                       uint32_t& x0, uint32_t& x1) {
  uint32_t k2 = k0 ^ k1 ^ 0x1BD11BDAu;
  x0 += k0; x1 += k1;
#define TFR(r) { x0 += x1; x1 = rotl32(x1, r); x1 ^= x0; }
  TFR(13) TFR(15) TFR(26) TFR(6)   x0 += k1; x1 += k2 + 1u;
  TFR(17) TFR(29) TFR(16) TFR(24)  x0 += k2; x1 += k0 + 2u;
  TFR(13) TFR(15) TFR(26) TFR(6)   x0 += k0; x1 += k1 + 3u;
  TFR(17) TFR(29) TFR(16) TFR(24)  x0 += k1; x1 += k2 + 4u;
  TFR(13) TFR(15) TFR(26) TFR(6)   x0 += k2; x1 += k0 + 5u;
#undef TFR
}

__device__ __forceinline__ float bits_to_u01(uint32_t bits) {
  return __fsub_rn(__uint_as_float((bits >> 9) | 0x3f800000u), 1.0f);
}

// XLA ErfInv32 (Giles), w = -log((1-x)(1+x)) exactly as ElementalIrEmitter
__device__ __forceinline__ float erfinv_f32(float x) {
  float w = -logf(__fmul_rn(__fsub_rn(1.0f, x), __fadd_rn(1.0f, x)));
  float p;
  if (w < 5.0f) {
    w = __fsub_rn(w, 2.5f);
    p = 2.81022636e-08f;
    p = __fadd_rn(__fmul_rn(p, w), 3.43273939e-07f);
    p = __fadd_rn(__fmul_rn(p, w), -3.5233877e-06f);
    p = __fadd_rn(__fmul_rn(p, w), -4.39150654e-06f);
    p = __fadd_rn(__fmul_rn(p, w), 0.00021858087f);
    p = __fadd_rn(__fmul_rn(p, w), -0.00125372503f);
    p = __fadd_rn(__fmul_rn(p, w), -0.00417768164f);
    p = __fadd_rn(__fmul_rn(p, w), 0.246640727f);
    p = __fadd_rn(__fmul_rn(p, w), 1.50140941f);
  } else {
    w = __fsub_rn(sqrtf(w), 3.0f);
    p = -0.000200214257f;
    p = __fadd_rn(__fmul_rn(p, w), 0.000100950558f);
    p = __fadd_rn(__fmul_rn(p, w), 0.00134934322f);
    p = __fadd_rn(__fmul_rn(p, w), -0.00367342844f);
    p = __fadd_rn(__fmul_rn(p, w), 0.00573950773f);
    p = __fadd_rn(__fmul_rn(p, w), -0.0076224613f);
    p = __fadd_rn(__fmul_rn(p, w), 0.00943887047f);
    p = __fadd_rn(__fmul_rn(p, w), 1.00167406f);
    p = __fadd_rn(__fmul_rn(p, w), 2.83297682f);
  }
  return __fmul_rn(p, x);
}

// fast sigmoid: 1/(1+exp(-x)) via native exp + native rcp (~1-2 ulp)
__device__ __forceinline__ float fast_sigmoid(float x) {
  float e = __expf(-x);
  return __builtin_amdgcn_rcpf(__fadd_rn(1.0f, e));
}

// DPP-based partial butterfly stage: x += dpp(x)
template <int CTRL>
__device__ __forceinline__ float dpp_add(float x) {
  int v = __builtin_amdgcn_update_dpp(0, __float_as_int(x), CTRL, 0xF, 0xF, true);
  return __fadd_rn(x, __int_as_float(v));
}
__device__ __forceinline__ float readlane_f(float x, int lane) {
  return __int_as_float(__builtin_amdgcn_readlane(__float_as_int(x), lane));
}

// ---------------- Kernel A: softmax-mixture mean/std + L(f32) ---------------
__global__ void prep_kernel(const float* __restrict__ mu,
                            const float* __restrict__ sig,
                            const float* __restrict__ pi,
                            float* __restrict__ sm, float* __restrict__ ss,
                            float* __restrict__ Lf) {
  int m = blockIdx.x * blockDim.x + threadIdx.x;
  if (m >= BB * NN) return;
  const float* pp = pi + m * KK;
  float mx = pp[0];
  for (int k = 1; k < KK; k++) mx = fmaxf(mx, pp[k]);
  float e[KK]; float s = 0.0f;
  for (int k = 0; k < KK; k++) { e[k] = expf(__fsub_rn(pp[k], mx)); s = __fadd_rn(s, e[k]); }
  float smv = 0.0f, ssv = 0.0f, eps = 0.0f;
  for (int k = 0; k < KK; k++) {
    float p = e[k] / s;
    smv = __fadd_rn(smv, __fmul_rn(p, mu[m * KK + k]));
    ssv = __fadd_rn(ssv, __fmul_rn(p, sig[m * KK + k]));
    eps = __fadd_rn(eps, pp[k]);
  }
  sm[m] = smv; ss[m] = ssv;
  float ep = fminf(fmaxf(eps, 1e-8f), 1.0f);
  float lep = logf(ep);
  float l1 = logf(__fsub_rn(1.0f, ep));
  Lf[m] = (float)((double)lep - (double)l1);
}

// -------- Kernel B: JAX partitionable-threefry RNG -> pm table + uniforms ----
__global__ void rng_kernel(const float* __restrict__ sm,
                           const float* __restrict__ ss,
                           float* __restrict__ pm, float* __restrict__ uacc) {
  int id = blockIdx.x * blockDim.x + threadIdx.x;
  if (id >= T_STEPS * BB * NN) return;
  int t = id >> 11;        // /2048
  int m = id & 2047;       // b*512+n

  uint32_t kk0 = 0u, kk1 = (uint32_t)t;
  tf2x32(0u, 42u, kk0, kk1);
  uint32_t n0 = 0u, n1 = 0u; tf2x32(kk0, kk1, n0, n1);   // k_noise
  uint32_t y0 = 0u, y1 = (uint32_t)m;
  tf2x32(n0, n1, y0, y1);
  uint32_t bits = y0 ^ y1;

  float u01 = bits_to_u01(bits);
  const float lo = -0.99999994f;  // nextafter(-1,0) f32; span rounds to 2.0f
  float u = fmaxf(lo, __fadd_rn(__fmul_rn(u01, 2.0f), lo));
  float z = __fmul_rn(1.41421356237309515f, erfinv_f32(u));
  pm[id] = __fadd_rn(sm[m], __fmul_rn(z, ss[m]));

  if (m < 4) {
    uint32_t u0 = 0u, u1 = 1u; tf2x32(kk0, kk1, u0, u1); // k_unif
    uint32_t c0 = 0u, c1 = (uint32_t)m;
    tf2x32(u0, u1, c0, c1);
    uacc[t * 4 + m] = bits_to_u01(c0 ^ c1);
  }
}

// ------- Kernel C: partial llt[t][b][j] = sum_{i in chunk} sgm(pm_i pm_j)*L[b,i]
template <int SPLIT>
__global__ __launch_bounds__(512) void ll_kernel(const float* __restrict__ pm,
                                                 const float* __restrict__ Lf,
                                                 const float* __restrict__ A0,
                                                 float* __restrict__ llt_p,
                                                 float* __restrict__ ll0_p) {
  constexpr int CH = NN / SPLIT;
  __shared__ float spm[CH];
  __shared__ float sLc[CH];
  int j = threadIdx.x;
  int bi = blockIdx.x;
  if (bi < TBTOT * SPLIT) {
    int tb = bi / SPLIT;
    int s = bi - tb * SPLIT;
    int b = tb & 3;
    int i0 = s * CH;
    if (j < CH) {
      spm[j] = pm[tb * NN + i0 + j];
      sLc[j] = Lf[b * NN + i0 + j];
    }
    float pmj = pm[tb * NN + j];
    __syncthreads();
    double acc = 0.0;
    #pragma unroll 8
    for (int i = 0; i < CH; i += 2) {
      float x0 = __fmul_rn(spm[i], pmj);
      float x1 = __fmul_rn(spm[i + 1], pmj);
      float t0 = __fmul_rn(fast_sigmoid(x0), sLc[i]);
      float t1 = __fmul_rn(fast_sigmoid(x1), sLc[i + 1]);
      acc += (double)__fadd_rn(t0, t1);
    }
    llt_p[(size_t)s * LLT_ELT + (size_t)tb * NN + j] = (float)acc;
  } else {
    int bi2 = bi - TBTOT * SPLIT;
    int b = bi2 / SPLIT;
    int s = bi2 - b * SPLIT;
    int i0 = s * CH;
    if (j < CH) sLc[j] = Lf[b * NN + i0 + j];
    __syncthreads();
    double acc = 0.0;
    #pragma unroll 4
    for (int i = 0; i < CH; i++) {
      acc += (double)A0[(size_t)(i0 + i) * NN + j] * (double)sLc[i];
    }
    ll0_p[s * (BB * NN) + b * NN + j] = (float)acc;
  }
}

// ------- Kernel C2: deterministic combine of f32 partials (f64 sum) ---------
template <int SPLIT>
__global__ __launch_bounds__(512) void combine_kernel(const float* __restrict__ llt_p,
                                                      const float* __restrict__ ll0_p,
                                                      float* __restrict__ llt,
                                                      float* __restrict__ ll0) {
  int bi = blockIdx.x;
  int j = threadIdx.x;
  if (bi < T_STEPS) {
    #pragma unroll
    for (int b = 0; b < BB; b++) {
      size_t idx = ((size_t)bi * BB + b) * NN + j;
      double a = (double)llt_p[idx];
      #pragma unroll
      for (int s = 1; s < SPLIT; s++) a += (double)llt_p[(size_t)s * LLT_ELT + idx];
      llt[idx] = (float)a;
    }
  } else {
    #pragma unroll
    for (int b = 0; b < BB; b++) {
      int idx = b * NN + j;
      double a = (double)ll0_p[idx];
      #pragma unroll
      for (int s = 1; s < SPLIT; s++) a += (double)ll0_p[s * (BB * NN) + idx];
      ll0[idx] = (float)a;
    }
  }
}

// ------- Kernel D: sequential MCMC chain, SINGLE WAVE, f32 rows -------------
// lane g owns j = 256k + 4g + c (k=0..1, c=0..3).  8KB/step (f32), depth-3
// register prefetch (3x32 VGPR -> no spill).  ts = sum_b row_b computed
// in-register (f64 from f32 rows); C[j] = sum_b llcur f64-incremental.
// Reduce: 4 DPP stages + readlane{0,16,32,48} (no LDS, no barrier).
#define CH_LOADF(BUF, T)                                                     \
  {                                                                          \
    _Pragma("unroll")                                                        \
    for (int b = 0; b < 4; b++) {                                            \
      _Pragma("unroll")                                                      \
      for (int k = 0; k < 2; k++)                                            \
        BUF[b][k] = llt4[(((size_t)(T) * 4 + b) * 2 + k) * 64 + g];          \
    }                                                                        \
  }

#define CH_ACCF(BUF, B)                                                      \
  {                                                                          \
    _Pragma("unroll")                                                        \
    for (int k = 0; k < 2; k++) {                                            \
      _Pragma("unroll")                                                      \
      for (int c = 0; c < 4; c++)                                            \
        C[k][c] += (double)BUF[B][k][c] - (double)cur[B][k][c];              \
      cur[B][k] = BUF[B][k];                                                 \
    }                                                                        \
  }

#define CH_STEPF(BUF, T)                                                     \
  {                                                                          \
    float4 ua = sua[T];                                                      \
    float ps = 0.0f;                                                         \
    _Pragma("unroll")                                                        \
    for (int k = 0; k < 2; k++) {                                            \
      _Pragma("unroll")                                                      \
      for (int c = 0; c < 4; c++) {                                          \
        double ts = ((double)BUF[0][k][c] + (double)BUF[1][k][c]) +          \
                    ((double)BUF[2][k][c] + (double)BUF[3][k][c]);           \
        float e = fminf(__expf((float)(ts - C[k][c])), 1.0f);                \
        ps = __fadd_rn(ps, e);                                               \
      }                                                                      \
    }                                                                        \
    ps = dpp_add<0xB1>(ps);   /* quad_perm [1,0,3,2]  : xor1 */              \
    ps = dpp_add<0x4E>(ps);   /* quad_perm [2,3,0,1]  : xor2 */              \
    ps = dpp_add<0x141>(ps);  /* ROW_HALF_MIRROR      : xor4-pairing */      \
    ps = dpp_add<0x140>(ps);  /* ROW_MIRROR           : xor8-pairing */      \
    float s0 = readlane_f(ps, 0), s1 = readlane_f(ps, 16);                   \
    float s2 = readlane_f(ps, 32), s3 = readlane_f(ps, 48);                  \
    float tot = __fadd_rn(__fadd_rn(s0, s1), __fadd_rn(s2, s3));             \
    float ratio = __fmul_rn(tot, 1.0f / 512.0f);                             \
    if (ua.x < ratio) { st.x = (T); CH_ACCF(BUF, 0) }                        \
    if (ua.y < ratio) { st.y = (T); CH_ACCF(BUF, 1) }                        \
    if (ua.z < ratio) { st.z = (T); CH_ACCF(BUF, 2) }                        \
    if (ua.w < ratio) { st.w = (T); CH_ACCF(BUF, 3) }                        \
    if (g == 0) sst[T] = st;                                                 \
  }

__global__ __launch_bounds__(64) void chain_kernel(const float* __restrict__ llt,
                                                   const float* __restrict__ ll0,
                                                   const float* __restrict__ uacc,
                                                   int* __restrict__ counts) {
  __shared__ float4 sua[T_STEPS];
  __shared__ int4 sst[T_STEPS];
  __shared__ int scnt[BB * (T_STEPS + 1)];
  int g = threadIdx.x;

  const float4* uacc4 = (const float4*)uacc;
  for (int t = g; t < T_STEPS; t += 64) sua[t] = uacc4[t];

  const f4* llt4 = (const f4*)llt;
  const f4* ll04 = (const f4*)ll0;

  f4 cur[4][2];
  #pragma unroll
  for (int b = 0; b < 4; b++)
    #pragma unroll
    for (int k = 0; k < 2; k++) cur[b][k] = ll04[(b * 2 + k) * 64 + g];
  double C[2][4];
  #pragma unroll
  for (int k = 0; k < 2; k++)
    #pragma unroll
    for (int c = 0; c < 4; c++)
      C[k][c] = ((double)cur[0][k][c] + (double)cur[1][k][c]) +
                ((double)cur[2][k][c] + (double)cur[3][k][c]);
  int4 st = make_int4(-1, -1, -1, -1);

  f4 R0[4][2], R1[4][2], R2[4][2];
  CH_LOADF(R0, 0)
  CH_LOADF(R1, 1)
  CH_LOADF(R2, 2)
  __syncthreads();  // single wave; orders sua writes (cheap)

  for (int t = 0; t < 99; t += 3) {
    CH_STEPF(R0, t)
    CH_LOADF(R0, t + 3)                        // t+3 <= 99 always
    CH_STEPF(R1, t + 1)
    if (t + 4 < T_STEPS) CH_LOADF(R1, t + 4)
    CH_STEPF(R2, t + 2)
    if (t + 5 < T_STEPS) CH_LOADF(R2, t + 5)
  }
  CH_STEPF(R0, 99)

  __syncthreads();
  for (int s = g; s < BB * (T_STEPS + 1); s += 64) scnt[s] = 0;
  __syncthreads();
  for (int t = g; t < T_STEPS; t += 64) {
    int4 s4 = sst[t];
    atomicAdd(&scnt[0 * (T_STEPS + 1) + s4.x + 1], 1);
    atomicAdd(&scnt[1 * (T_STEPS + 1) + s4.y + 1], 1);
    atomicAdd(&scnt[2 * (T_STEPS + 1) + s4.z + 1], 1);
    atomicAdd(&scnt[3 * (T_STEPS + 1) + s4.w + 1], 1);
  }
  __syncthreads();
  for (int s = g; s < BB * (T_STEPS + 1); s += 64) counts[s] = scnt[s];
}

// ---------------- Kernel E: acc = sum_states count * A_state / num_samples --
__global__ __launch_bounds__(512) void out_kernel(const float* __restrict__ pm,
                                                  const float* __restrict__ A0,
                                                  const int* __restrict__ counts,
                                                  float* __restrict__ out) {
  __shared__ int scnt[T_STEPS + 1];
  int b = blockIdx.x >> 9;
  int i = blockIdx.x & 511;
  int j = threadIdx.x;
  if (j < T_STEPS + 1) scnt[j] = counts[b * (T_STEPS + 1) + j];
  __syncthreads();
  float r = (float)scnt[0] * A0[(size_t)i * NN + j];
  #pragma unroll 4
  for (int t = 0; t < T_STEPS; t++) {
    int c = scnt[t + 1];
    if (c) {
      float x = __fmul_rn(pm[(size_t)(t * BB + b) * NN + i],
                          pm[(size_t)(t * BB + b) * NN + j]);
      r += (float)c * fast_sigmoid(x);
    }
  }
  out[((size_t)b * NN + i) * NN + j] = r * 0.01f;
}

extern "C" void kernel_launch(void* const* d_in, const int* in_sizes, int n_in,
                              void* d_out, int out_size, void* d_ws, size_t ws_size,
                              hipStream_t stream) {
  const float* mu  = (const float*)d_in[0];
  const float* sig = (const float*)d_in[1];
  const float* pi  = (const float*)d_in[2];
  const float* A0  = (const float*)d_in[3];

  char* ws = (char*)d_ws;
  size_t off = 0;
  auto alloc = [&](size_t bytes) -> char* {
    char* p = ws + off;
    off += (bytes + 255) & ~(size_t)255;
    return p;
  };
  float* llt  = (float*)alloc(LLT_ELT * 4);            // 819,200
  float* ll0  = (float*)alloc(BB * NN * 4);            // 8,192
  float* pm   = (float*)alloc(LLT_ELT * 4);            // 819,200
  float* Lf   = (float*)alloc(BB * NN * 4);
  float* sm   = (float*)alloc(BB * NN * 4);
  float* ssv  = (float*)alloc(BB * NN * 4);
  float* uacc = (float*)alloc(T_STEPS * 4 * 4);
  int*   cnts = (int*)alloc(BB * (T_STEPS + 1) * 4);
  size_t fixed_end = off;
  float* outp = (float*)d_out;

  // choose SPLIT by available scratch for partial buffers (f32 now)
  size_t part4 = 4 * LLT_ELT * 4 + 4 * BB * NN * 4 + 1024;
  size_t part2 = 2 * LLT_ELT * 4 + 2 * BB * NN * 4 + 1024;
  int split = (ws_size >= fixed_end + part4) ? 4
            : (ws_size >= fixed_end + part2) ? 2 : 1;

  float* llt_p;
  float* ll0_p;
  if (split > 1) {
    llt_p = (float*)alloc((size_t)split * LLT_ELT * 4);
    ll0_p = (float*)alloc((size_t)split * BB * NN * 4);
  } else {
    llt_p = llt;  // write directly, no combine needed for llt
    ll0_p = ll0;
  }

  prep_kernel<<<8, 256, 0, stream>>>(mu, sig, pi, sm, ssv, Lf);
  rng_kernel<<<(T_STEPS * BB * NN + 255) / 256, 256, 0, stream>>>(sm, ssv, pm, uacc);
  if (split == 4) {
    ll_kernel<4><<<(TBTOT + BB) * 4, 512, 0, stream>>>(pm, Lf, A0, llt_p, ll0_p);
    combine_kernel<4><<<T_STEPS + 1, 512, 0, stream>>>(llt_p, ll0_p, llt, ll0);
  } else if (split == 2) {
    ll_kernel<2><<<(TBTOT + BB) * 2, 512, 0, stream>>>(pm, Lf, A0, llt_p, ll0_p);
    combine_kernel<2><<<T_STEPS + 1, 512, 0, stream>>>(llt_p, ll0_p, llt, ll0);
  } else {
    ll_kernel<1><<<TBTOT + BB, 512, 0, stream>>>(pm, Lf, A0, llt_p, ll0_p);
  }
  chain_kernel<<<1, 64, 0, stream>>>(llt, ll0, uacc, cnts);
  out_kernel<<<BB * NN, 512, 0, stream>>>(pm, A0, cnts, outp);
}